// Round 16
// baseline (892.332 us; speedup 1.0000x reference)
//
#include <hip/hip_runtime.h>
#include <hip/hip_bf16.h>

#define NN 8192
#define DD 1024
#define KK 16384  // 2*NN

using half8 = __attribute__((ext_vector_type(8))) _Float16;
using half4 = __attribute__((ext_vector_type(4))) _Float16;
using f32x4 = __attribute__((ext_vector_type(4))) float;
using u32x4 = __attribute__((ext_vector_type(4))) unsigned int;

// ---- static device buffers ----
__device__ __align__(16) _Float16 g_gh[(size_t)NN * DD];   // gen fp16
__device__ __align__(16) _Float16 g_ph[(size_t)NN * DD];   // pos fp16
__device__ __align__(16) _Float16 g_vt[(size_t)DD * KK];   // VT[d][k]: k<NN pos, k>=NN gen
__device__ float g_gn[NN];
__device__ float g_pn[NN];
// distances stored u16 fixed-point: u = round(d*1024), diag saturates to 65535
__device__ __align__(16) unsigned short g_datt[(size_t)NN * NN];  // 134 MB
__device__ __align__(16) unsigned short g_drep[(size_t)NN * NN];  // 134 MB
__device__ __align__(16) _Float16 g_w[(size_t)NN * KK];    // combined weights, 268 MB
__device__ float g_part[2 * (size_t)NN * DD];              // split-K partials, 64 MB

typedef const __attribute__((address_space(1))) void GV;
typedef __attribute__((address_space(3))) void LV;
__device__ inline void gload16(const void* g, void* l) {
    __builtin_amdgcn_global_load_lds((GV*)g, (LV*)l, 16, 0, 0);
}

// ---- prep: fp16 convert + row norms ----
__global__ __launch_bounds__(256) void k_conv(const float* __restrict__ gen,
                                              const float* __restrict__ pos) {
    int b = blockIdx.x;
    int r = b & (NN - 1);
    const float* src = (b < NN) ? gen : pos;
    _Float16* dsth = (b < NN) ? g_gh : g_ph;
    float* dstn = (b < NN) ? g_gn : g_pn;
    int t = threadIdx.x;
    const float4* s4 = (const float4*)(src + (size_t)r * DD);
    float4 x = s4[t];
    half4 h = {(_Float16)x.x, (_Float16)x.y, (_Float16)x.z, (_Float16)x.w};
    *(half4*)(dsth + (size_t)r * DD + t * 4) = h;
    float s = x.x * x.x + x.y * x.y + x.z * x.z + x.w * x.w;
#pragma unroll
    for (int off = 32; off; off >>= 1) s += __shfl_xor(s, off);
    __shared__ float red[4];
    if ((t & 63) == 0) red[t >> 6] = s;
    __syncthreads();
    if (t == 0) dstn[r] = red[0] + red[1] + red[2] + red[3];
}

// ---- prep: build VT[d][k] ----
__global__ __launch_bounds__(256) void k_tr(const float* __restrict__ pos,
                                            const float* __restrict__ gen) {
    int jt = blockIdx.x;  // 0..127
    int dt = blockIdx.y;  // 0..15
    int z = blockIdx.z;   // 0: pos, 1: gen
    const float* src = z ? gen : pos;
    size_t cbase = z ? (size_t)NN : 0;
    __shared__ _Float16 tile[64][68];
    int t = threadIdx.x;
    int j0 = jt * 64, d0 = dt * 64;
#pragma unroll
    for (int p = 0; p < 4; p++) {
        int idx = t + p * 256;
        int r = idx >> 4;
        int c4 = idx & 15;
        float4 x = *(const float4*)(src + (size_t)(j0 + r) * DD + d0 + c4 * 4);
        tile[r][c4 * 4 + 0] = (_Float16)x.x;
        tile[r][c4 * 4 + 1] = (_Float16)x.y;
        tile[r][c4 * 4 + 2] = (_Float16)x.z;
        tile[r][c4 * 4 + 3] = (_Float16)x.w;
    }
    __syncthreads();
#pragma unroll
    for (int p = 0; p < 4; p++) {
        int idx = t + p * 256;
        int d = idx >> 4;
        int j4 = idx & 15;
        half4 h = {tile[j4 * 4 + 0][d], tile[j4 * 4 + 1][d],
                   tile[j4 * 4 + 2][d], tile[j4 * 4 + 3][d]};
        *(half4*)(g_vt + (size_t)(d0 + d) * KK + cbase + j0 + j4 * 4) = h;
    }
}

#define MFMA16(A_, B_, C_) __builtin_amdgcn_mfma_f32_16x16x32_f16(A_, B_, C_, 0, 0, 0)
#define BAR() __builtin_amdgcn_s_barrier()
#define LGKM0() do { asm volatile("s_waitcnt lgkmcnt(0)" ::: "memory"); \
                     __builtin_amdgcn_sched_barrier(0); } while (0)
#define VM4() asm volatile("s_waitcnt vmcnt(4)" ::: "memory")
#define VM0() asm volatile("s_waitcnt vmcnt(0)" ::: "memory")

// ==== 256x256 MFMA GEMM core — 8-phase window schedule (round-8 proven) ====
template <int LDK>
__device__ inline void gemm_core(const _Float16* __restrict__ A,
                                 const _Float16* __restrict__ B,
                                 int arow0, int brow0, int kcol0, int ntiles,
                                 _Float16* lds, f32x4 acc[8][4]) {
    int t = threadIdx.x;
    int w = t >> 6, lane = t & 63;
    int wm = w >> 2, wn = w & 3;   // 2x4 wave grid; per-wave 128x64 output
    int q = lane >> 4, li = lane & 15;
    _Float16* sA = lds;
    _Float16* sB = lds + 4 * 8192;

    int offA[8], offB[4];
#pragma unroll
    for (int m = 0; m < 8; ++m) {
        int row = wm * 128 + m * 16 + li;
        offA[m] = row * 32 + (q ^ ((row >> 1) & 3)) * 8;
    }
#pragma unroll
    for (int n = 0; n < 4; ++n) {
        int row = wn * 64 + n * 16 + li;
        offB[n] = row * 32 + (q ^ ((row >> 1) & 3)) * 8;
    }

    int rbase = w * 16 + (lane >> 2);
    int csrc = (lane & 3) ^ ((rbase >> 1) & 3);
    const _Float16* gA0 = A + (size_t)(arow0 + rbase) * LDK + kcol0 + csrc * 8;
    const _Float16* gA1 = gA0 + (size_t)128 * LDK;
    const _Float16* gB0 = B + (size_t)(brow0 + rbase) * LDK + kcol0 + csrc * 8;
    const _Float16* gB1 = gB0 + (size_t)128 * LDK;
    int ldst = w * 512;

#define STAGE_A(tile_) do { \
    gload16(gA0 + (size_t)(tile_) * 32, sA + ((tile_) & 3) * 8192 + ldst); \
    gload16(gA1 + (size_t)(tile_) * 32, sA + ((tile_) & 3) * 8192 + 4096 + ldst); } while (0)
#define STAGE_B(tile_) do { \
    gload16(gB0 + (size_t)(tile_) * 32, sB + ((tile_) & 3) * 8192 + ldst); \
    gload16(gB1 + (size_t)(tile_) * 32, sB + ((tile_) & 3) * 8192 + 4096 + ldst); } while (0)

    STAGE_A(0); STAGE_B(0); STAGE_A(1); STAGE_B(1);
    VM4();
    BAR();

    int nwin = ntiles >> 1;
    half8 af[4], bf[4], af2[4];
#pragma unroll 2
    for (int wi = 0; wi < nwin; ++wi) {
        int t0 = 2 * wi, t1 = t0 + 1;
        const _Float16* a0 = sA + (t0 & 3) * 8192;
        const _Float16* b0 = sB + (t0 & 3) * 8192;
        const _Float16* a1 = sA + (t1 & 3) * 8192;
        const _Float16* b1 = sB + (t1 & 3) * 8192;
        // P1
#pragma unroll
        for (int m = 0; m < 4; ++m) af[m] = *(const half8*)(a0 + offA[m]);
#pragma unroll
        for (int n = 0; n < 4; ++n) bf[n] = *(const half8*)(b0 + offB[n]);
        if (t0 + 2 < ntiles) STAGE_A(t0 + 2);
        BAR();
        LGKM0();
        __builtin_amdgcn_s_setprio(1);
#pragma unroll
        for (int m = 0; m < 4; ++m)
#pragma unroll
            for (int n = 0; n < 4; ++n)
                acc[m][n] = MFMA16(af[m], bf[n], acc[m][n]);
        __builtin_amdgcn_s_setprio(0);
        BAR();
        // P2
#pragma unroll
        for (int m = 0; m < 4; ++m) af2[m] = *(const half8*)(a0 + offA[m + 4]);
        if (t0 + 2 < ntiles) STAGE_B(t0 + 2);
        BAR();
        LGKM0();
        __builtin_amdgcn_s_setprio(1);
#pragma unroll
        for (int m = 0; m < 4; ++m)
#pragma unroll
            for (int n = 0; n < 4; ++n)
                acc[m + 4][n] = MFMA16(af2[m], bf[n], acc[m + 4][n]);
        __builtin_amdgcn_s_setprio(0);
        if (wi < nwin - 1) VM4(); else VM0();
        BAR();
        // P3
#pragma unroll
        for (int m = 0; m < 4; ++m) af[m] = *(const half8*)(a1 + offA[m]);
#pragma unroll
        for (int n = 0; n < 4; ++n) bf[n] = *(const half8*)(b1 + offB[n]);
        if (t1 + 2 < ntiles) STAGE_A(t1 + 2);
        BAR();
        LGKM0();
        __builtin_amdgcn_s_setprio(1);
#pragma unroll
        for (int m = 0; m < 4; ++m)
#pragma unroll
            for (int n = 0; n < 4; ++n)
                acc[m][n] = MFMA16(af[m], bf[n], acc[m][n]);
        __builtin_amdgcn_s_setprio(0);
        BAR();
        // P4
#pragma unroll
        for (int m = 0; m < 4; ++m) af2[m] = *(const half8*)(a1 + offA[m + 4]);
        if (t1 + 2 < ntiles) STAGE_B(t1 + 2);
        BAR();
        LGKM0();
        __builtin_amdgcn_s_setprio(1);
#pragma unroll
        for (int m = 0; m < 4; ++m)
#pragma unroll
            for (int n = 0; n < 4; ++n)
                acc[m + 4][n] = MFMA16(af2[m], bf[n], acc[m + 4][n]);
        __builtin_amdgcn_s_setprio(0);
        if (wi < nwin - 1) {
            VM4();
            BAR();
        }
    }
#undef STAGE_A
#undef STAGE_B
}

// ---- distance matrices: 1552 blocks = 1024 att + 528 rep upper-triangle.
// nt stores (r14-proven): D streams bypass cache; consumers run much later.
__global__ __launch_bounds__(512, 2) void k_qk2() {
    extern __shared__ _Float16 lds[];
    int id = blockIdx.x;                     // 0..1551
    id = (id & 7) * 194 + (id >> 3);         // XCD swizzle (1552 = 8*194, bijective)
    int rep, rt, ct;
    if (id < 1024) {
        rep = 0; rt = id >> 5; ct = id & 31;
    } else {
        rep = 1;
        int k = id - 1024;                   // 0..527, upper triangle rt>=ct
        int r = (int)((sqrtf(8.0f * (float)k + 1.0f) - 1.0f) * 0.5f);
        while ((r + 1) * (r + 2) / 2 <= k) ++r;
        while (r * (r + 1) / 2 > k) --r;
        rt = r; ct = k - r * (r + 1) / 2;    // ct <= rt
    }
    const _Float16* A = g_gh;
    const _Float16* B = rep ? g_gh : g_ph;
    const float* An = g_gn;
    const float* Bn = rep ? g_gn : g_pn;
    unsigned short* outp = rep ? g_drep : g_datt;

    f32x4 acc[8][4] = {};
    gemm_core<DD>(A, B, rt * 256, ct * 256, 0, DD / 32, lds, acc);
    __syncthreads();  // all waves done with GEMM LDS before repack reuse

    int t = threadIdx.x, w = t >> 6, lane = t & 63;
    int wm = w >> 2, wn = w & 3, q = lane >> 4, li = lane & 15;
    unsigned short* sd = (unsigned short*)lds;  // 256x256 u16 = 128 KB
    float bnv[4];
#pragma unroll
    for (int n = 0; n < 4; ++n) bnv[n] = Bn[ct * 256 + wn * 64 + n * 16 + li];
    float anv[8][4];
#pragma unroll
    for (int m = 0; m < 8; ++m)
#pragma unroll
        for (int r = 0; r < 4; ++r)
            anv[m][r] = An[rt * 256 + wm * 128 + m * 16 + q * 4 + r];

    // pass 1: normal repack + store to (rt,ct)
#pragma unroll
    for (int m = 0; m < 8; ++m) {
#pragma unroll
        for (int r = 0; r < 4; ++r) {
            int row = wm * 128 + m * 16 + q * 4 + r;
#pragma unroll
            for (int n = 0; n < 4; ++n) {
                int col = wn * 64 + n * 16 + li;
                float dsq = anv[m][r] + bnv[n] - 2.0f * acc[m][n][r];
                float d = sqrtf(fmaxf(dsq, 0.0f));
                if (rep && (rt * 256 + row) == (ct * 256 + col)) d = 1e30f;
                float dv = fminf(d * 1024.0f + 0.5f, 65535.0f);
                sd[row * 256 + col] = (unsigned short)(int)dv;
            }
        }
    }
    __syncthreads();
    {
        const u32x4* s4 = (const u32x4*)sd;
        int row16 = t >> 5, chunk = t & 31;
#pragma unroll
        for (int i = 0; i < 16; ++i) {
            int lrow = i * 16 + row16;
            u32x4 v = s4[lrow * 32 + chunk];
            __builtin_nontemporal_store(
                v, (u32x4*)(outp + (size_t)(rt * 256 + lrow) * NN + ct * 256) + chunk);
        }
    }

    // pass 2 (rep off-diagonal): transposed repack + store to (ct,rt)
    if (rep && rt != ct) {
        __syncthreads();
#pragma unroll
        for (int m = 0; m < 8; ++m) {
#pragma unroll
            for (int r = 0; r < 4; ++r) {
                int row = wm * 128 + m * 16 + q * 4 + r;
#pragma unroll
                for (int n = 0; n < 4; ++n) {
                    int col = wn * 64 + n * 16 + li;
                    float dsq = anv[m][r] + bnv[n] - 2.0f * acc[m][n][r];
                    float d = sqrtf(fmaxf(dsq, 0.0f));
                    float dv = fminf(d * 1024.0f + 0.5f, 65535.0f);
                    sd[col * 256 + row] = (unsigned short)(int)dv;  // transposed
                }
            }
        }
        __syncthreads();
        const u32x4* s4 = (const u32x4*)sd;
        int row16 = t >> 5, chunk = t & 31;
#pragma unroll
        for (int i = 0; i < 16; ++i) {
            int lrow = i * 16 + row16;
            u32x4 v = s4[lrow * 32 + chunk];
            __builtin_nontemporal_store(
                v, (u32x4*)(outp + (size_t)(ct * 256 + lrow) * NN + rt * 256) + chunk);
        }
    }
}

// ---- fused stats + weights: nt u16 reads, 1-exp power trick, nt W writes ----
// exp(-50x)=e5^10, exp(-20x)=e5^4 where e5=exp(-5x): 1 transcendental + 4 muls
// replaces 3 transcendentals (both passes).
__global__ __launch_bounds__(256) void k_sw(const float* __restrict__ scales) {
    int i = blockIdx.x, t = threadIdx.x;
    const u32x4* ra = (const u32x4*)(g_datt + (size_t)i * NN);  // 1024 u32x4/row
    const u32x4* rr = (const u32x4*)(g_drep + (size_t)i * NN);
    float va[32], vr[32];
    float mna = 1e30f, mnr = 1e30f;
    const float SC = 1.0f / 1024.0f;
#pragma unroll
    for (int p = 0; p < 4; ++p) {
        u32x4 x = __builtin_nontemporal_load(&ra[t + p * 256]);
        u32x4 y = __builtin_nontemporal_load(&rr[t + p * 256]);
#pragma unroll
        for (int u = 0; u < 4; ++u) {
            float a0 = (float)(x[u] & 0xFFFFu) * SC;
            float a1 = (float)(x[u] >> 16) * SC;
            float r0 = (float)(y[u] & 0xFFFFu) * SC;
            float r1 = (float)(y[u] >> 16) * SC;
            va[p * 8 + u * 2 + 0] = a0; va[p * 8 + u * 2 + 1] = a1;
            vr[p * 8 + u * 2 + 0] = r0; vr[p * 8 + u * 2 + 1] = r1;
            mna = fminf(mna, fminf(a0, a1));
            mnr = fminf(mnr, fminf(r0, r1));
        }
    }
#pragma unroll
    for (int off = 32; off; off >>= 1) {
        mna = fminf(mna, __shfl_xor(mna, off));
        mnr = fminf(mnr, __shfl_xor(mnr, off));
    }
    __shared__ float sm[2][4];
    __shared__ float ss[6][4];
    int wv = t >> 6;
    if ((t & 63) == 0) { sm[0][wv] = mna; sm[1][wv] = mnr; }
    __syncthreads();
    mna = fminf(fminf(sm[0][0], sm[0][1]), fminf(sm[0][2], sm[0][3]));
    mnr = fminf(fminf(sm[1][0], sm[1][1]), fminf(sm[1][2], sm[1][3]));
    float s0 = 0.f, s1 = 0.f, s2 = 0.f, s3 = 0.f, s4 = 0.f, s5 = 0.f;
#pragma unroll
    for (int k = 0; k < 32; ++k) {
        float e5 = __expf((va[k] - mna) * -5.0f);
        float e10 = e5 * e5, e20 = e10 * e10;
        s0 += e20 * e20 * e10; s1 += e20; s2 += e5;
        float f5 = __expf((vr[k] - mnr) * -5.0f);
        float f10 = f5 * f5, f20 = f10 * f10;
        s3 += f20 * f20 * f10; s4 += f20; s5 += f5;
    }
#pragma unroll
    for (int off = 32; off; off >>= 1) {
        s0 += __shfl_xor(s0, off); s1 += __shfl_xor(s1, off); s2 += __shfl_xor(s2, off);
        s3 += __shfl_xor(s3, off); s4 += __shfl_xor(s4, off); s5 += __shfl_xor(s5, off);
    }
    if ((t & 63) == 0) {
        ss[0][wv] = s0; ss[1][wv] = s1; ss[2][wv] = s2;
        ss[3][wv] = s3; ss[4][wv] = s4; ss[5][wv] = s5;
    }
    __syncthreads();
    float l0 = ss[0][0] + ss[0][1] + ss[0][2] + ss[0][3];
    float l1 = ss[1][0] + ss[1][1] + ss[1][2] + ss[1][3];
    float l2 = ss[2][0] + ss[2][1] + ss[2][2] + ss[2][3];
    float l3 = ss[3][0] + ss[3][1] + ss[3][2] + ss[3][3];
    float l4 = ss[4][0] + ss[4][1] + ss[4][2] + ss[4][3];
    float l5 = ss[5][0] + ss[5][1] + ss[5][2] + ss[5][3];
    float i0 = 1.0f / (3.0f * fmaxf(scales[0], 1e-6f));
    float i1 = 1.0f / (3.0f * fmaxf(scales[1], 1e-6f));
    float i2 = 1.0f / (3.0f * fmaxf(scales[2], 1e-6f));
    float ca0 = i0 / l0, ca1 = i1 / l1, ca2 = i2 / l2;
    float cr0 = -i0 / l3, cr1 = -i1 / l4, cr2 = -i2 / l5;
    _Float16* wa = g_w + (size_t)i * KK;
    _Float16* wr = wa + NN;
#pragma unroll
    for (int p = 0; p < 4; ++p) {
        union { half8 h; u32x4 u; } ha, hr;
#pragma unroll
        for (int qq = 0; qq < 8; ++qq) {
            float e5 = __expf((va[p * 8 + qq] - mna) * -5.0f);
            float e10 = e5 * e5, e20 = e10 * e10;
            ha.h[qq] = (_Float16)(ca0 * (e20 * e20 * e10) + ca1 * e20 + ca2 * e5);
            float f5 = __expf((vr[p * 8 + qq] - mnr) * -5.0f);
            float f10 = f5 * f5, f20 = f10 * f10;
            hr.h[qq] = (_Float16)(cr0 * (f20 * f20 * f10) + cr1 * f20 + cr2 * f5);
        }
        __builtin_nontemporal_store(ha.u, (u32x4*)(wa + (size_t)(t + p * 256) * 8));
        __builtin_nontemporal_store(hr.u, (u32x4*)(wr + (size_t)(t + p * 256) * 8));
    }
}

// ---- out_partial[z] = W[:, zK/2:(z+1)K/2] @ VT^T slice : split-K=2 ----
// XCD grouping: 4 ct-blocks sharing one W row-panel on the SAME XCD.
__global__ __launch_bounds__(512, 2) void k_gemm2() {
    extern __shared__ _Float16 lds[];
    int L = blockIdx.y * 4 + blockIdx.x;   // 0..127 launched order
    int rt = (L & 7) + 8 * (L >> 5);       // 0..31
    int ct = (L >> 3) & 3;                 // 0..3
    int z = blockIdx.z;
    f32x4 acc[8][4] = {};
    gemm_core<KK>(g_w, g_vt, rt * 256, ct * 256, z * (KK / 2), (KK / 2) / 32, lds, acc);
    float* outp = g_part + (size_t)z * NN * DD;
    int t = threadIdx.x, w = t >> 6, lane = t & 63;
    int wm = w >> 2, wn = w & 3, q = lane >> 4, li = lane & 15;
#pragma unroll
    for (int m = 0; m < 8; ++m) {
#pragma unroll
        for (int r = 0; r < 4; ++r) {
            int gi = rt * 256 + wm * 128 + m * 16 + q * 4 + r;
            float* orow = outp + (size_t)gi * DD;
#pragma unroll
            for (int n = 0; n < 4; ++n) {
                int gj = ct * 256 + wn * 64 + n * 16 + li;
                orow[gj] = acc[m][n][r];
            }
        }
    }
}

__global__ __launch_bounds__(256) void k_red(float* __restrict__ out) {
    size_t base = (size_t)blockIdx.x * 256 + threadIdx.x;
    const float4* p0 = (const float4*)g_part;
    const float4* p1 = (const float4*)(g_part + (size_t)NN * DD);
    float4* o4 = (float4*)out;
#pragma unroll
    for (int p = 0; p < 4; ++p) {
        size_t idx = base + (size_t)p * 524288;
        float4 a = p0[idx], b = p1[idx];
        float4 c = {a.x + b.x, a.y + b.y, a.z + b.z, a.w + b.w};
        o4[idx] = c;
    }
}

extern "C" void kernel_launch(void* const* d_in, const int* in_sizes, int n_in,
                              void* d_out, int out_size, void* d_ws, size_t ws_size,
                              hipStream_t stream) {
    (void)in_sizes; (void)n_in; (void)d_ws; (void)ws_size; (void)out_size;
    const float* gen = (const float*)d_in[0];
    const float* pos = (const float*)d_in[1];
    const float* scales = (const float*)d_in[2];

    (void)hipFuncSetAttribute((const void*)k_qk2, hipFuncAttributeMaxDynamicSharedMemorySize, 131072);
    (void)hipFuncSetAttribute((const void*)k_gemm2, hipFuncAttributeMaxDynamicSharedMemorySize, 131072);

    k_conv<<<dim3(2 * NN), 256, 0, stream>>>(gen, pos);
    k_tr<<<dim3(128, 16, 2), 256, 0, stream>>>(pos, gen);
    k_qk2<<<dim3(1552), 512, 131072, stream>>>();
    k_sw<<<dim3(NN), 256, 0, stream>>>(scales);
    k_gemm2<<<dim3(4, 32, 2), 512, 131072, stream>>>();
    k_red<<<dim3(2048), 256, 0, stream>>>((float*)d_out);
}

// Round 17
// 808.679 us; speedup vs baseline: 1.1034x; 1.1034x over previous
//
#include <hip/hip_runtime.h>
#include <hip/hip_bf16.h>

#define NN 8192
#define DD 1024
#define KK 16384  // 2*NN

using half8 = __attribute__((ext_vector_type(8))) _Float16;
using half4 = __attribute__((ext_vector_type(4))) _Float16;
using f32x4 = __attribute__((ext_vector_type(4))) float;
using u32x4 = __attribute__((ext_vector_type(4))) unsigned int;

// ---- static device buffers ----
__device__ __align__(16) _Float16 g_gh[(size_t)NN * DD];   // gen fp16
__device__ __align__(16) _Float16 g_ph[(size_t)NN * DD];   // pos fp16
__device__ __align__(16) _Float16 g_vt[(size_t)DD * KK];   // VT[d][k]: k<NN pos, k>=NN gen
__device__ float g_gn[NN];
__device__ float g_pn[NN];
// distances stored u16 fixed-point: u = round(d*1024), diag saturates to 65535
__device__ __align__(16) unsigned short g_datt[(size_t)NN * NN];  // 134 MB
__device__ __align__(16) unsigned short g_drep[(size_t)NN * NN];  // 134 MB
__device__ __align__(16) _Float16 g_w[(size_t)NN * KK];    // combined weights, 268 MB
__device__ float g_part[2 * (size_t)NN * DD];              // split-K partials, 64 MB

typedef const __attribute__((address_space(1))) void GV;
typedef __attribute__((address_space(3))) void LV;
__device__ inline void gload16(const void* g, void* l) {
    __builtin_amdgcn_global_load_lds((GV*)g, (LV*)l, 16, 0, 0);
}

// ---- prep: fp16 convert + row norms ----
__global__ __launch_bounds__(256) void k_conv(const float* __restrict__ gen,
                                              const float* __restrict__ pos) {
    int b = blockIdx.x;
    int r = b & (NN - 1);
    const float* src = (b < NN) ? gen : pos;
    _Float16* dsth = (b < NN) ? g_gh : g_ph;
    float* dstn = (b < NN) ? g_gn : g_pn;
    int t = threadIdx.x;
    const float4* s4 = (const float4*)(src + (size_t)r * DD);
    float4 x = s4[t];
    half4 h = {(_Float16)x.x, (_Float16)x.y, (_Float16)x.z, (_Float16)x.w};
    *(half4*)(dsth + (size_t)r * DD + t * 4) = h;
    float s = x.x * x.x + x.y * x.y + x.z * x.z + x.w * x.w;
#pragma unroll
    for (int off = 32; off; off >>= 1) s += __shfl_xor(s, off);
    __shared__ float red[4];
    if ((t & 63) == 0) red[t >> 6] = s;
    __syncthreads();
    if (t == 0) dstn[r] = red[0] + red[1] + red[2] + red[3];
}

// ---- prep: build VT[d][k] ----
__global__ __launch_bounds__(256) void k_tr(const float* __restrict__ pos,
                                            const float* __restrict__ gen) {
    int jt = blockIdx.x;  // 0..127
    int dt = blockIdx.y;  // 0..15
    int z = blockIdx.z;   // 0: pos, 1: gen
    const float* src = z ? gen : pos;
    size_t cbase = z ? (size_t)NN : 0;
    __shared__ _Float16 tile[64][68];
    int t = threadIdx.x;
    int j0 = jt * 64, d0 = dt * 64;
#pragma unroll
    for (int p = 0; p < 4; p++) {
        int idx = t + p * 256;
        int r = idx >> 4;
        int c4 = idx & 15;
        float4 x = *(const float4*)(src + (size_t)(j0 + r) * DD + d0 + c4 * 4);
        tile[r][c4 * 4 + 0] = (_Float16)x.x;
        tile[r][c4 * 4 + 1] = (_Float16)x.y;
        tile[r][c4 * 4 + 2] = (_Float16)x.z;
        tile[r][c4 * 4 + 3] = (_Float16)x.w;
    }
    __syncthreads();
#pragma unroll
    for (int p = 0; p < 4; p++) {
        int idx = t + p * 256;
        int d = idx >> 4;
        int j4 = idx & 15;
        half4 h = {tile[j4 * 4 + 0][d], tile[j4 * 4 + 1][d],
                   tile[j4 * 4 + 2][d], tile[j4 * 4 + 3][d]};
        *(half4*)(g_vt + (size_t)(d0 + d) * KK + cbase + j0 + j4 * 4) = h;
    }
}

#define MFMA16(A_, B_, C_) __builtin_amdgcn_mfma_f32_16x16x32_f16(A_, B_, C_, 0, 0, 0)
#define BAR() __builtin_amdgcn_s_barrier()
#define LGKM0() do { asm volatile("s_waitcnt lgkmcnt(0)" ::: "memory"); \
                     __builtin_amdgcn_sched_barrier(0); } while (0)
#define VM4() asm volatile("s_waitcnt vmcnt(4)" ::: "memory")
#define VM0() asm volatile("s_waitcnt vmcnt(0)" ::: "memory")

// ==== 256x256 MFMA GEMM core — 8-phase window schedule (round-8 proven) ====
template <int LDK>
__device__ inline void gemm_core(const _Float16* __restrict__ A,
                                 const _Float16* __restrict__ B,
                                 int arow0, int brow0, int kcol0, int ntiles,
                                 _Float16* lds, f32x4 acc[8][4]) {
    int t = threadIdx.x;
    int w = t >> 6, lane = t & 63;
    int wm = w >> 2, wn = w & 3;   // 2x4 wave grid; per-wave 128x64 output
    int q = lane >> 4, li = lane & 15;
    _Float16* sA = lds;
    _Float16* sB = lds + 4 * 8192;

    int offA[8], offB[4];
#pragma unroll
    for (int m = 0; m < 8; ++m) {
        int row = wm * 128 + m * 16 + li;
        offA[m] = row * 32 + (q ^ ((row >> 1) & 3)) * 8;
    }
#pragma unroll
    for (int n = 0; n < 4; ++n) {
        int row = wn * 64 + n * 16 + li;
        offB[n] = row * 32 + (q ^ ((row >> 1) & 3)) * 8;
    }

    int rbase = w * 16 + (lane >> 2);
    int csrc = (lane & 3) ^ ((rbase >> 1) & 3);
    const _Float16* gA0 = A + (size_t)(arow0 + rbase) * LDK + kcol0 + csrc * 8;
    const _Float16* gA1 = gA0 + (size_t)128 * LDK;
    const _Float16* gB0 = B + (size_t)(brow0 + rbase) * LDK + kcol0 + csrc * 8;
    const _Float16* gB1 = gB0 + (size_t)128 * LDK;
    int ldst = w * 512;

#define STAGE_A(tile_) do { \
    gload16(gA0 + (size_t)(tile_) * 32, sA + ((tile_) & 3) * 8192 + ldst); \
    gload16(gA1 + (size_t)(tile_) * 32, sA + ((tile_) & 3) * 8192 + 4096 + ldst); } while (0)
#define STAGE_B(tile_) do { \
    gload16(gB0 + (size_t)(tile_) * 32, sB + ((tile_) & 3) * 8192 + ldst); \
    gload16(gB1 + (size_t)(tile_) * 32, sB + ((tile_) & 3) * 8192 + 4096 + ldst); } while (0)

    STAGE_A(0); STAGE_B(0); STAGE_A(1); STAGE_B(1);
    VM4();
    BAR();

    int nwin = ntiles >> 1;
    half8 af[4], bf[4], af2[4];
#pragma unroll 2
    for (int wi = 0; wi < nwin; ++wi) {
        int t0 = 2 * wi, t1 = t0 + 1;
        const _Float16* a0 = sA + (t0 & 3) * 8192;
        const _Float16* b0 = sB + (t0 & 3) * 8192;
        const _Float16* a1 = sA + (t1 & 3) * 8192;
        const _Float16* b1 = sB + (t1 & 3) * 8192;
        // P1
#pragma unroll
        for (int m = 0; m < 4; ++m) af[m] = *(const half8*)(a0 + offA[m]);
#pragma unroll
        for (int n = 0; n < 4; ++n) bf[n] = *(const half8*)(b0 + offB[n]);
        if (t0 + 2 < ntiles) STAGE_A(t0 + 2);
        BAR();
        LGKM0();
        __builtin_amdgcn_s_setprio(1);
#pragma unroll
        for (int m = 0; m < 4; ++m)
#pragma unroll
            for (int n = 0; n < 4; ++n)
                acc[m][n] = MFMA16(af[m], bf[n], acc[m][n]);
        __builtin_amdgcn_s_setprio(0);
        BAR();
        // P2
#pragma unroll
        for (int m = 0; m < 4; ++m) af2[m] = *(const half8*)(a0 + offA[m + 4]);
        if (t0 + 2 < ntiles) STAGE_B(t0 + 2);
        BAR();
        LGKM0();
        __builtin_amdgcn_s_setprio(1);
#pragma unroll
        for (int m = 0; m < 4; ++m)
#pragma unroll
            for (int n = 0; n < 4; ++n)
                acc[m + 4][n] = MFMA16(af2[m], bf[n], acc[m + 4][n]);
        __builtin_amdgcn_s_setprio(0);
        if (wi < nwin - 1) VM4(); else VM0();
        BAR();
        // P3
#pragma unroll
        for (int m = 0; m < 4; ++m) af[m] = *(const half8*)(a1 + offA[m]);
#pragma unroll
        for (int n = 0; n < 4; ++n) bf[n] = *(const half8*)(b1 + offB[n]);
        if (t1 + 2 < ntiles) STAGE_A(t1 + 2);
        BAR();
        LGKM0();
        __builtin_amdgcn_s_setprio(1);
#pragma unroll
        for (int m = 0; m < 4; ++m)
#pragma unroll
            for (int n = 0; n < 4; ++n)
                acc[m][n] = MFMA16(af[m], bf[n], acc[m][n]);
        __builtin_amdgcn_s_setprio(0);
        BAR();
        // P4
#pragma unroll
        for (int m = 0; m < 4; ++m) af2[m] = *(const half8*)(a1 + offA[m + 4]);
        if (t1 + 2 < ntiles) STAGE_B(t1 + 2);
        BAR();
        LGKM0();
        __builtin_amdgcn_s_setprio(1);
#pragma unroll
        for (int m = 0; m < 4; ++m)
#pragma unroll
            for (int n = 0; n < 4; ++n)
                acc[m + 4][n] = MFMA16(af2[m], bf[n], acc[m + 4][n]);
        __builtin_amdgcn_s_setprio(0);
        if (wi < nwin - 1) {
            VM4();
            BAR();
        }
    }
#undef STAGE_A
#undef STAGE_B
}

// ---- distance matrices: 1552 blocks = 1024 att + 528 rep upper-triangle.
// Rep is symmetric (gen x gen): compute rt>=ct only; write (rt,ct) and,
// for off-diagonal blocks, also (ct,rt) via a second transposed LDS repack
// from the same accumulators. nt stores (r14-proven best).
__global__ __launch_bounds__(512, 2) void k_qk2() {
    extern __shared__ _Float16 lds[];
    int id = blockIdx.x;                     // 0..1551
    id = (id & 7) * 194 + (id >> 3);         // XCD swizzle (1552 = 8*194, bijective)
    int rep, rt, ct;
    if (id < 1024) {
        rep = 0; rt = id >> 5; ct = id & 31;
    } else {
        rep = 1;
        int k = id - 1024;                   // 0..527, upper triangle rt>=ct
        int r = (int)((sqrtf(8.0f * (float)k + 1.0f) - 1.0f) * 0.5f);
        while ((r + 1) * (r + 2) / 2 <= k) ++r;
        while (r * (r + 1) / 2 > k) --r;
        rt = r; ct = k - r * (r + 1) / 2;    // ct <= rt
    }
    const _Float16* A = g_gh;
    const _Float16* B = rep ? g_gh : g_ph;
    const float* An = g_gn;
    const float* Bn = rep ? g_gn : g_pn;
    unsigned short* outp = rep ? g_drep : g_datt;

    f32x4 acc[8][4] = {};
    gemm_core<DD>(A, B, rt * 256, ct * 256, 0, DD / 32, lds, acc);
    __syncthreads();  // all waves done with GEMM LDS before repack reuse

    int t = threadIdx.x, w = t >> 6, lane = t & 63;
    int wm = w >> 2, wn = w & 3, q = lane >> 4, li = lane & 15;
    unsigned short* sd = (unsigned short*)lds;  // 256x256 u16 = 128 KB
    float bnv[4];
#pragma unroll
    for (int n = 0; n < 4; ++n) bnv[n] = Bn[ct * 256 + wn * 64 + n * 16 + li];
    float anv[8][4];
#pragma unroll
    for (int m = 0; m < 8; ++m)
#pragma unroll
        for (int r = 0; r < 4; ++r)
            anv[m][r] = An[rt * 256 + wm * 128 + m * 16 + q * 4 + r];

    // pass 1: normal repack + store to (rt,ct)
#pragma unroll
    for (int m = 0; m < 8; ++m) {
#pragma unroll
        for (int r = 0; r < 4; ++r) {
            int row = wm * 128 + m * 16 + q * 4 + r;
#pragma unroll
            for (int n = 0; n < 4; ++n) {
                int col = wn * 64 + n * 16 + li;
                float dsq = anv[m][r] + bnv[n] - 2.0f * acc[m][n][r];
                float d = sqrtf(fmaxf(dsq, 0.0f));
                if (rep && (rt * 256 + row) == (ct * 256 + col)) d = 1e30f;
                float dv = fminf(d * 1024.0f + 0.5f, 65535.0f);
                sd[row * 256 + col] = (unsigned short)(int)dv;
            }
        }
    }
    __syncthreads();
    {
        const u32x4* s4 = (const u32x4*)sd;
        int row16 = t >> 5, chunk = t & 31;
#pragma unroll
        for (int i = 0; i < 16; ++i) {
            int lrow = i * 16 + row16;
            u32x4 v = s4[lrow * 32 + chunk];
            __builtin_nontemporal_store(
                v, (u32x4*)(outp + (size_t)(rt * 256 + lrow) * NN + ct * 256) + chunk);
        }
    }

    // pass 2 (rep off-diagonal): transposed repack + store to (ct,rt)
    if (rep && rt != ct) {
        __syncthreads();
#pragma unroll
        for (int m = 0; m < 8; ++m) {
#pragma unroll
            for (int r = 0; r < 4; ++r) {
                int row = wm * 128 + m * 16 + q * 4 + r;
#pragma unroll
                for (int n = 0; n < 4; ++n) {
                    int col = wn * 64 + n * 16 + li;
                    float dsq = anv[m][r] + bnv[n] - 2.0f * acc[m][n][r];
                    float d = sqrtf(fmaxf(dsq, 0.0f));
                    float dv = fminf(d * 1024.0f + 0.5f, 65535.0f);
                    sd[col * 256 + row] = (unsigned short)(int)dv;  // transposed
                }
            }
        }
        __syncthreads();
        const u32x4* s4 = (const u32x4*)sd;
        int row16 = t >> 5, chunk = t & 31;
#pragma unroll
        for (int i = 0; i < 16; ++i) {
            int lrow = i * 16 + row16;
            u32x4 v = s4[lrow * 32 + chunk];
            __builtin_nontemporal_store(
                v, (u32x4*)(outp + (size_t)(ct * 256 + lrow) * NN + rt * 256) + chunk);
        }
    }
}

// ---- fused stats + weights: u16 nt reads, one pass, nt half8 W writes ----
__global__ __launch_bounds__(256) void k_sw(const float* __restrict__ scales) {
    int i = blockIdx.x, t = threadIdx.x;
    const u32x4* ra = (const u32x4*)(g_datt + (size_t)i * NN);  // 1024 u32x4/row
    const u32x4* rr = (const u32x4*)(g_drep + (size_t)i * NN);
    float va[32], vr[32];
    float mna = 1e30f, mnr = 1e30f;
    const float SC = 1.0f / 1024.0f;
#pragma unroll
    for (int p = 0; p < 4; ++p) {
        u32x4 x = __builtin_nontemporal_load(&ra[t + p * 256]);
        u32x4 y = __builtin_nontemporal_load(&rr[t + p * 256]);
#pragma unroll
        for (int u = 0; u < 4; ++u) {
            float a0 = (float)(x[u] & 0xFFFFu) * SC;
            float a1 = (float)(x[u] >> 16) * SC;
            float r0 = (float)(y[u] & 0xFFFFu) * SC;
            float r1 = (float)(y[u] >> 16) * SC;
            va[p * 8 + u * 2 + 0] = a0; va[p * 8 + u * 2 + 1] = a1;
            vr[p * 8 + u * 2 + 0] = r0; vr[p * 8 + u * 2 + 1] = r1;
            mna = fminf(mna, fminf(a0, a1));
            mnr = fminf(mnr, fminf(r0, r1));
        }
    }
#pragma unroll
    for (int off = 32; off; off >>= 1) {
        mna = fminf(mna, __shfl_xor(mna, off));
        mnr = fminf(mnr, __shfl_xor(mnr, off));
    }
    __shared__ float sm[2][4];
    __shared__ float ss[6][4];
    int wv = t >> 6;
    if ((t & 63) == 0) { sm[0][wv] = mna; sm[1][wv] = mnr; }
    __syncthreads();
    mna = fminf(fminf(sm[0][0], sm[0][1]), fminf(sm[0][2], sm[0][3]));
    mnr = fminf(fminf(sm[1][0], sm[1][1]), fminf(sm[1][2], sm[1][3]));
    float s0 = 0.f, s1 = 0.f, s2 = 0.f, s3 = 0.f, s4 = 0.f, s5 = 0.f;
#pragma unroll
    for (int k = 0; k < 32; ++k) {
        float da = va[k] - mna;
        s0 += __expf(da * -50.0f); s1 += __expf(da * -20.0f); s2 += __expf(da * -5.0f);
        float dr = vr[k] - mnr;
        s3 += __expf(dr * -50.0f); s4 += __expf(dr * -20.0f); s5 += __expf(dr * -5.0f);
    }
#pragma unroll
    for (int off = 32; off; off >>= 1) {
        s0 += __shfl_xor(s0, off); s1 += __shfl_xor(s1, off); s2 += __shfl_xor(s2, off);
        s3 += __shfl_xor(s3, off); s4 += __shfl_xor(s4, off); s5 += __shfl_xor(s5, off);
    }
    if ((t & 63) == 0) {
        ss[0][wv] = s0; ss[1][wv] = s1; ss[2][wv] = s2;
        ss[3][wv] = s3; ss[4][wv] = s4; ss[5][wv] = s5;
    }
    __syncthreads();
    float l0 = ss[0][0] + ss[0][1] + ss[0][2] + ss[0][3];
    float l1 = ss[1][0] + ss[1][1] + ss[1][2] + ss[1][3];
    float l2 = ss[2][0] + ss[2][1] + ss[2][2] + ss[2][3];
    float l3 = ss[3][0] + ss[3][1] + ss[3][2] + ss[3][3];
    float l4 = ss[4][0] + ss[4][1] + ss[4][2] + ss[4][3];
    float l5 = ss[5][0] + ss[5][1] + ss[5][2] + ss[5][3];
    float i0 = 1.0f / (3.0f * fmaxf(scales[0], 1e-6f));
    float i1 = 1.0f / (3.0f * fmaxf(scales[1], 1e-6f));
    float i2 = 1.0f / (3.0f * fmaxf(scales[2], 1e-6f));
    float ca0 = i0 / l0, ca1 = i1 / l1, ca2 = i2 / l2;
    float cr0 = -i0 / l3, cr1 = -i1 / l4, cr2 = -i2 / l5;
    _Float16* wa = g_w + (size_t)i * KK;
    _Float16* wr = wa + NN;
#pragma unroll
    for (int p = 0; p < 4; ++p) {
        union { half8 h; u32x4 u; } ha, hr;
#pragma unroll
        for (int qq = 0; qq < 8; ++qq) {
            float da = va[p * 8 + qq] - mna;
            ha.h[qq] = (_Float16)(ca0 * __expf(da * -50.0f) + ca1 * __expf(da * -20.0f) +
                                  ca2 * __expf(da * -5.0f));
            float dr = vr[p * 8 + qq] - mnr;
            hr.h[qq] = (_Float16)(cr0 * __expf(dr * -50.0f) + cr1 * __expf(dr * -20.0f) +
                                  cr2 * __expf(dr * -5.0f));
        }
        __builtin_nontemporal_store(ha.u, (u32x4*)(wa + (size_t)(t + p * 256) * 8));
        __builtin_nontemporal_store(hr.u, (u32x4*)(wr + (size_t)(t + p * 256) * 8));
    }
}

// ---- out_partial[z] = W[:, zK/2:(z+1)K/2] @ VT^T slice : split-K=2 ----
__global__ __launch_bounds__(512, 2) void k_gemm2() {
    extern __shared__ _Float16 lds[];
    int id = blockIdx.y * 4 + blockIdx.x;  // 0..127
    id = (id & 7) * 16 + (id >> 3);        // XCD swizzle (128%8==0)
    int rt = id >> 2, ct = id & 3;
    int z = blockIdx.z;
    f32x4 acc[8][4] = {};
    gemm_core<KK>(g_w, g_vt, rt * 256, ct * 256, z * (KK / 2), (KK / 2) / 32, lds, acc);
    float* outp = g_part + (size_t)z * NN * DD;
    int t = threadIdx.x, w = t >> 6, lane = t & 63;
    int wm = w >> 2, wn = w & 3, q = lane >> 4, li = lane & 15;
#pragma unroll
    for (int m = 0; m < 8; ++m) {
#pragma unroll
        for (int r = 0; r < 4; ++r) {
            int gi = rt * 256 + wm * 128 + m * 16 + q * 4 + r;
            float* orow = outp + (size_t)gi * DD;
#pragma unroll
            for (int n = 0; n < 4; ++n) {
                int gj = ct * 256 + wn * 64 + n * 16 + li;
                orow[gj] = acc[m][n][r];
            }
        }
    }
}

__global__ __launch_bounds__(256) void k_red(float* __restrict__ out) {
    size_t base = (size_t)blockIdx.x * 256 + threadIdx.x;
    const float4* p0 = (const float4*)g_part;
    const float4* p1 = (const float4*)(g_part + (size_t)NN * DD);
    float4* o4 = (float4*)out;
#pragma unroll
    for (int p = 0; p < 4; ++p) {
        size_t idx = base + (size_t)p * 524288;
        float4 a = p0[idx], b = p1[idx];
        float4 c = {a.x + b.x, a.y + b.y, a.z + b.z, a.w + b.w};
        o4[idx] = c;
    }
}

extern "C" void kernel_launch(void* const* d_in, const int* in_sizes, int n_in,
                              void* d_out, int out_size, void* d_ws, size_t ws_size,
                              hipStream_t stream) {
    (void)in_sizes; (void)n_in; (void)d_ws; (void)ws_size; (void)out_size;
    const float* gen = (const float*)d_in[0];
    const float* pos = (const float*)d_in[1];
    const float* scales = (const float*)d_in[2];

    (void)hipFuncSetAttribute((const void*)k_qk2, hipFuncAttributeMaxDynamicSharedMemorySize, 131072);
    (void)hipFuncSetAttribute((const void*)k_gemm2, hipFuncAttributeMaxDynamicSharedMemorySize, 131072);

    k_conv<<<dim3(2 * NN), 256, 0, stream>>>(gen, pos);
    k_tr<<<dim3(128, 16, 2), 256, 0, stream>>>(pos, gen);
    k_qk2<<<dim3(1552), 512, 131072, stream>>>();
    k_sw<<<dim3(NN), 256, 0, stream>>>(scales);
    k_gemm2<<<dim3(4, 32, 2), 512, 131072, stream>>>();
    k_red<<<dim3(2048), 256, 0, stream>>>((float*)d_out);
}